// Round 4
// baseline (724.220 us; speedup 1.0000x reference)
//
#include <hip/hip_runtime.h>
#include <stdint.h>

#define T_  2048
#define H_  1024
#define NH_ 16
#define HD_ 64

typedef __bf16 bf16x8 __attribute__((ext_vector_type(8)));
typedef float  f32x4  __attribute__((ext_vector_type(4)));

__device__ __forceinline__ unsigned short f2bf(float f) {
  unsigned u = __builtin_bit_cast(unsigned, f);
  u += 0x7fffu + ((u >> 16) & 1u);          // RNE
  return (unsigned short)(u >> 16);
}

// ---------------- W_eff = W + 2.0 * B@A  (LoRA fold), store bf16 ----------------
__global__ void prep_weights(const float* __restrict__ Wq, const float* __restrict__ Aq, const float* __restrict__ Bq,
                             const float* __restrict__ Wk, const float* __restrict__ Ak, const float* __restrict__ Bk,
                             const float* __restrict__ Wv, const float* __restrict__ Av, const float* __restrict__ Bv,
                             unsigned short* __restrict__ Weff) {
  int p = blockIdx.y;
  const float* W = (p == 0) ? Wq : (p == 1) ? Wk : Wv;
  const float* A = (p == 0) ? Aq : (p == 1) ? Ak : Av;
  const float* B = (p == 0) ? Bq : (p == 1) ? Bk : Bv;
  int idx = blockIdx.x * 256 + threadIdx.x;      // 0 .. 1M-1
  int o = idx >> 10, h = idx & 1023;
  float acc = W[idx];
#pragma unroll
  for (int r = 0; r < 8; ++r)
    acc += 2.0f * B[o * 8 + r] * A[r * H_ + h];  // SCALING = 16/8 = 2
  Weff[p * (H_ * H_) + idx] = f2bf(acc);
}

// ---------------- x fp32 -> bf16 ----------------
__global__ void convert_x(const float* __restrict__ x, unsigned short* __restrict__ Xb) {
  int i = (blockIdx.x * 256 + threadIdx.x) * 8;
  f32x4 a = *(const f32x4*)(x + i);
  f32x4 c = *(const f32x4*)(x + i + 4);
  uint4 rv;
  rv.x = (unsigned)f2bf(a[0]) | ((unsigned)f2bf(a[1]) << 16);
  rv.y = (unsigned)f2bf(a[2]) | ((unsigned)f2bf(a[3]) << 16);
  rv.z = (unsigned)f2bf(c[0]) | ((unsigned)f2bf(c[1]) << 16);
  rv.w = (unsigned)f2bf(c[2]) | ((unsigned)f2bf(c[3]) << 16);
  *(uint4*)(Xb + i) = rv;
}

// ---------------- QKV GEMM: C[m,n] = sum_k Xb[m,k] * Weff[n,k] (+bias) ----------------
// Epilogue: q scaled by 1/8 (softmax scale folded); V stored PRE-PERMUTED so attn's
// PV A-fragment is a single contiguous 16B load (slot map = P's natural map).
#define BM 128
#define BN 128
#define BK 32
__global__ __launch_bounds__(256) void gemm_qkv(
    const unsigned short* __restrict__ Xb, const unsigned short* __restrict__ Weff,
    const float* __restrict__ bq, const float* __restrict__ bk, const float* __restrict__ bv,
    unsigned short* __restrict__ qq, unsigned short* __restrict__ kk, unsigned short* __restrict__ vP) {
  __shared__ __align__(16) unsigned short As[BM][BK];
  __shared__ __align__(16) unsigned short Bs[BN][BK];
  int tid = threadIdx.x;
  int m0 = blockIdx.y * BM;
  int n0 = blockIdx.x * BN;
  int w = tid >> 6, l = tid & 63;
  int wm = w >> 1, wn = w & 1;
  int lr = l & 15, lg = l >> 4;

  f32x4 acc[4][4] = {};
  for (int kt = 0; kt < H_ / BK; ++kt) {
    __syncthreads();
#pragma unroll
    for (int i = 0; i < 2; ++i) {
      int c = tid + i * 256;                     // 512 16B chunks per tile
      int row = c >> 2, ks = (c & 3) * 8;
      const unsigned short* ga = Xb + (size_t)(m0 + row) * H_ + kt * BK + ks;
      const unsigned short* gb = Weff + (size_t)(n0 + row) * H_ + kt * BK + ks;
      __builtin_amdgcn_global_load_lds((const __attribute__((address_space(1))) void*)ga,
                                       (__attribute__((address_space(3))) void*)(&As[0][0] + c * 8), 16, 0, 0);
      __builtin_amdgcn_global_load_lds((const __attribute__((address_space(1))) void*)gb,
                                       (__attribute__((address_space(3))) void*)(&Bs[0][0] + c * 8), 16, 0, 0);
    }
    __syncthreads();
    bf16x8 af[4], bf[4];
#pragma unroll
    for (int f = 0; f < 4; ++f) {
      af[f] = *(const bf16x8*)&As[wm * 64 + f * 16 + lr][lg * 8];
      bf[f] = *(const bf16x8*)&Bs[wn * 64 + f * 16 + lr][lg * 8];
    }
#pragma unroll
    for (int fm = 0; fm < 4; ++fm)
#pragma unroll
      for (int fn = 0; fn < 4; ++fn)
        acc[fm][fn] = __builtin_amdgcn_mfma_f32_16x16x32_bf16(af[fm], bf[fn], acc[fm][fn], 0, 0, 0);
  }

  int p = n0 >> 10;
  const float* bias = (p == 0) ? bq : (p == 1) ? bk : bv;
#pragma unroll
  for (int fm = 0; fm < 4; ++fm) {
    int mbase = m0 + wm * 64 + fm * 16 + lg * 4;
#pragma unroll
    for (int fn = 0; fn < 4; ++fn) {
      int o = (n0 & 1023) + wn * 64 + fn * 16 + lr;
      int hh = o >> 6, d = o & 63;
      float bv_ = bias[o];
#pragma unroll
      for (int r = 0; r < 4; ++r) {
        int m = mbase + r;
        int bb = m >> 11, t = m & 2047;
        float v = acc[fm][fn][r] + bv_;
        size_t bh = (size_t)(bb * NH_ + hh);
        if (p == 0) {
          qq[(bh * T_ + t) * HD_ + d] = f2bf(v * 0.125f);   // fold 1/sqrt(64)
        } else if (p == 1) {
          kk[(bh * T_ + t) * HD_ + d] = f2bf(v);
        } else {
          // permuted position within 32-key tile: slot(g,j,hi) = g*8 + j + hi*4
          int r5 = t & 31;
          int within = ((r5 >> 2) & 3) * 8 + (r5 & 3) + ((r5 >> 4) << 2);
          vP[(bh * HD_ + d) * T_ + (t & ~31) + within] = f2bf(v);
        }
      }
    }
  }
}

// ---------------- causal flash attention, split-K across 4 waves ----------------
// Block = one (bh, qt) 32-row Q-tile. Wave w strides k-tiles ti = w, w+4, ...
// with private (m,l,O) state; LDS combine at the end. Register ping-pong
// double-buffer for K/V/mask. Zero-shuffle P->PV (V pre-permuted).
__global__ __launch_bounds__(256, 4) void attn_fwd(
    const unsigned short* __restrict__ qq, const unsigned short* __restrict__ kk,
    const unsigned short* __restrict__ vP, const float* __restrict__ mask,
    float* __restrict__ out) {
  __shared__ __align__(16) f32x4 accS[4][2][4][64];   // [wave][u][dn][lane] 32 KB
  __shared__ float mS[4][2][64];                      // 2 KB
  __shared__ float lS[4][2][64];                      // 2 KB

  int w = threadIdx.x >> 6, l = threadIdx.x & 63;
  int bid = blockIdx.x;
  int qt = 63 - (bid >> 6);                      // big tiles dispatch first
  int bh = bid & 63;
  int b = bh >> 4, h = bh & 15;
  int t0 = qt * 32;
  int nt = qt + 1;
  int lr = l & 15, g = l >> 4;
  const float L2E = 1.4426950408889634f;
  const float NINF = -__builtin_inff();

  const unsigned short* Kp = kk + (size_t)bh * T_ * HD_;
  const unsigned short* Vp = vP + (size_t)bh * HD_ * T_;
  const float* mp = mask + b * T_;
  const unsigned short* Qp = qq + ((size_t)bh * T_ + t0) * HD_;

  bf16x8 qf[2][2];
#pragma unroll
  for (int u = 0; u < 2; ++u)
#pragma unroll
    for (int hs = 0; hs < 2; ++hs)
      qf[u][hs] = *(const bf16x8*)(Qp + (u * 16 + lr) * HD_ + hs * 32 + g * 8);

  f32x4 accO[2][4] = {};
  float m_run[2] = {NINF, NINF};
  float l_run[2] = {0.f, 0.f};

  // ping-pong buffers (named, static-indexed)
  bf16x8 kA0[2], kA1[2], vA[4], kB0[2], kB1[2], vB[4];
  f32x4 mA0, mA1, mB0, mB1;

  auto load_tile = [&](int k0, bf16x8 (&kd0)[2], bf16x8 (&kd1)[2], bf16x8 (&vd)[4],
                       f32x4& md0, f32x4& md1) {
#pragma unroll
    for (int hs = 0; hs < 2; ++hs) {
      kd0[hs] = *(const bf16x8*)(Kp + (size_t)(k0 + lr) * HD_ + hs * 32 + g * 8);
      kd1[hs] = *(const bf16x8*)(Kp + (size_t)(k0 + 16 + lr) * HD_ + hs * 32 + g * 8);
    }
#pragma unroll
    for (int dn = 0; dn < 4; ++dn)
      vd[dn] = *(const bf16x8*)(Vp + (size_t)(dn * 16 + lr) * T_ + k0 + g * 8);
    md0 = *(const f32x4*)(mp + k0 + g * 4);
    md1 = *(const f32x4*)(mp + k0 + 16 + g * 4);
  };

  auto step = [&](int ti, bf16x8 (&kc0)[2], bf16x8 (&kc1)[2], bf16x8 (&vc)[4],
                  f32x4& mc0, f32x4& mc1,
                  bf16x8 (&kn0)[2], bf16x8 (&kn1)[2], bf16x8 (&vn)[4],
                  f32x4& mn0, f32x4& mn1) {
    int k0 = ti * 32;
    f32x4 s0[2] = {{0.f,0.f,0.f,0.f},{0.f,0.f,0.f,0.f}};
    f32x4 s1[2] = {{0.f,0.f,0.f,0.f},{0.f,0.f,0.f,0.f}};
    __builtin_amdgcn_s_setprio(1);
#pragma unroll
    for (int u = 0; u < 2; ++u)
#pragma unroll
      for (int hs = 0; hs < 2; ++hs) {
        s0[u] = __builtin_amdgcn_mfma_f32_16x16x32_bf16(kc0[hs], qf[u][hs], s0[u], 0, 0, 0);
        s1[u] = __builtin_amdgcn_mfma_f32_16x16x32_bf16(kc1[hs], qf[u][hs], s1[u], 0, 0, 0);
      }
    __builtin_amdgcn_s_setprio(0);
    // issue next striped tile's loads early: latency hides under softmax+PV
    int k1 = k0 + 128;
    if (k1 < nt * 32) load_tile(k1, kn0, kn1, vn, mn0, mn1);

    bool diag = (ti == nt - 1);
#pragma unroll
    for (int u = 0; u < 2; ++u) {
      float sc0[4], sc1[4];
      if (diag) {
        int qrow = t0 + u * 16 + lr;
#pragma unroll
        for (int r = 0; r < 4; ++r) {
          int ka = k0 + g * 4 + r;
          sc0[r] = (ka <= qrow)      ? s0[u][r] + mc0[r] : NINF;
          sc1[r] = (ka + 16 <= qrow) ? s1[u][r] + mc1[r] : NINF;
        }
      } else {
#pragma unroll
        for (int r = 0; r < 4; ++r) {
          sc0[r] = s0[u][r] + mc0[r];
          sc1[r] = s1[u][r] + mc1[r];
        }
      }
      float pm = fmaxf(fmaxf(fmaxf(sc0[0], sc0[1]), fmaxf(sc0[2], sc0[3])),
                       fmaxf(fmaxf(sc1[0], sc1[1]), fmaxf(sc1[2], sc1[3])));
      pm = fmaxf(pm, __shfl_xor(pm, 16));
      pm = fmaxf(pm, __shfl_xor(pm, 32));
      // defer-max (T13, THR=8)
      if (!__all(pm <= m_run[u] + 8.f)) {
        float m_new = fmaxf(m_run[u], pm);
        float alpha = exp2f((m_run[u] - m_new) * L2E);
        l_run[u] *= alpha;
#pragma unroll
        for (int dn = 0; dn < 4; ++dn)
#pragma unroll
          for (int r = 0; r < 4; ++r) accO[u][dn][r] *= alpha;
        m_run[u] = m_new;
      }
      float p0[4], p1[4], rsl = 0.f;
#pragma unroll
      for (int r = 0; r < 4; ++r) {
        p0[r] = exp2f((sc0[r] - m_run[u]) * L2E);
        p1[r] = exp2f((sc1[r] - m_run[u]) * L2E);
        rsl += p0[r] + p1[r];
      }
      l_run[u] += rsl;                            // lane-local partial; reduced in combine
      bf16x8 pv_;
#pragma unroll
      for (int r = 0; r < 4; ++r) {
        pv_[r]     = (__bf16)p0[r];
        pv_[4 + r] = (__bf16)p1[r];
      }
      __builtin_amdgcn_s_setprio(1);
#pragma unroll
      for (int dn = 0; dn < 4; ++dn)
        accO[u][dn] = __builtin_amdgcn_mfma_f32_16x16x32_bf16(vc[dn], pv_, accO[u][dn], 0, 0, 0);
      __builtin_amdgcn_s_setprio(0);
    }
  };

  if (w < nt) {
    load_tile(w * 32, kA0, kA1, vA, mA0, mA1);
    int ti = w;
    for (;;) {
      step(ti, kA0, kA1, vA, mA0, mA1, kB0, kB1, vB, mB0, mB1);
      ti += 4; if (ti >= nt) break;
      step(ti, kB0, kB1, vB, mB0, mB1, kA0, kA1, vA, mA0, mA1);
      ti += 4; if (ti >= nt) break;
    }
  }

  // ---- combine the 4 waves' partials ----
#pragma unroll
  for (int u = 0; u < 2; ++u) {
    mS[w][u][l] = m_run[u];
    lS[w][u][l] = l_run[u];
#pragma unroll
    for (int dn = 0; dn < 4; ++dn) accS[w][u][dn][l] = accO[u][dn];
  }
  __syncthreads();

#pragma unroll
  for (int u = 0; u < 2; ++u) {
    float m0 = mS[0][u][l], m1 = mS[1][u][l], m2 = mS[2][u][l], m3 = mS[3][u][l];
    float M = fmaxf(fmaxf(m0, m1), fmaxf(m2, m3));
    float a0 = exp2f((m0 - M) * L2E), a1 = exp2f((m1 - M) * L2E);
    float a2 = exp2f((m2 - M) * L2E), a3 = exp2f((m3 - M) * L2E);
    float Ls = a0 * lS[0][u][l] + a1 * lS[1][u][l] + a2 * lS[2][u][l] + a3 * lS[3][u][l];
    Ls += __shfl_xor(Ls, 16);
    Ls += __shfl_xor(Ls, 32);
    f32x4 o0 = accS[0][u][w][l], o1 = accS[1][u][w][l];
    f32x4 o2 = accS[2][u][w][l], o3 = accS[3][u][w][l];
    float inv = 1.0f / Ls;
    f32x4 ov;
#pragma unroll
    for (int r = 0; r < 4; ++r)
      ov[r] = (a0 * o0[r] + a1 * o1[r] + a2 * o2[r] + a3 * o3[r]) * inv;
    float* op = out + ((size_t)b * T_ + t0 + u * 16 + lr) * H_ + h * HD_ + w * 16 + g * 4;
    *(f32x4*)op = ov;
  }
}

extern "C" void kernel_launch(void* const* d_in, const int* in_sizes, int n_in,
                              void* d_out, int out_size, void* d_ws, size_t ws_size,
                              hipStream_t stream) {
  const float* x    = (const float*)d_in[0];
  const float* mask = (const float*)d_in[1];
  const float* Wq = (const float*)d_in[2];
  const float* bq = (const float*)d_in[3];
  const float* Aq = (const float*)d_in[4];
  const float* Bq = (const float*)d_in[5];
  const float* Wk = (const float*)d_in[6];
  const float* bk = (const float*)d_in[7];
  const float* Ak = (const float*)d_in[8];
  const float* Bk = (const float*)d_in[9];
  const float* Wv = (const float*)d_in[10];
  const float* bv = (const float*)d_in[11];
  const float* Av = (const float*)d_in[12];
  const float* Bv = (const float*)d_in[13];
  float* out = (float*)d_out;

  char* ws = (char*)d_ws;
  unsigned short* Xb   = (unsigned short*)(ws);                   // 16 MB  [8192][1024]
  unsigned short* Weff = (unsigned short*)(ws + (16u << 20));     //  6 MB  [3][1024][1024]
  unsigned short* qq   = (unsigned short*)(ws + (22u << 20));     // 16 MB  [4][16][2048][64]
  unsigned short* kk   = (unsigned short*)(ws + (38u << 20));     // 16 MB  [4][16][2048][64]
  unsigned short* vP   = (unsigned short*)(ws + (54u << 20));     // 16 MB  [4][16][64][2048] (permuted tiles)

  prep_weights<<<dim3(4096, 3), 256, 0, stream>>>(Wq, Aq, Bq, Wk, Ak, Bk, Wv, Av, Bv, Weff);
  convert_x<<<4096, 256, 0, stream>>>(x, Xb);
  gemm_qkv<<<dim3(24, 64), 256, 0, stream>>>(Xb, Weff, bq, bk, bv, qq, kk, vP);
  attn_fwd<<<4096, 256, 0, stream>>>(qq, kk, vP, mask, out);
}

// Round 5
// 392.401 us; speedup vs baseline: 1.8456x; 1.8456x over previous
//
#include <hip/hip_runtime.h>
#include <stdint.h>

#define T_  2048
#define H_  1024
#define NH_ 16
#define HD_ 64

typedef __bf16 bf16x8 __attribute__((ext_vector_type(8)));
typedef float  f32x4  __attribute__((ext_vector_type(4)));

__device__ __forceinline__ unsigned short f2bf(float f) {
  unsigned u = __builtin_bit_cast(unsigned, f);
  u += 0x7fffu + ((u >> 16) & 1u);          // RNE
  return (unsigned short)(u >> 16);
}

// ---------------- W_eff = W + 2.0 * B@A  (LoRA fold), store bf16 ----------------
__global__ void prep_weights(const float* __restrict__ Wq, const float* __restrict__ Aq, const float* __restrict__ Bq,
                             const float* __restrict__ Wk, const float* __restrict__ Ak, const float* __restrict__ Bk,
                             const float* __restrict__ Wv, const float* __restrict__ Av, const float* __restrict__ Bv,
                             unsigned short* __restrict__ Weff) {
  int p = blockIdx.y;
  const float* W = (p == 0) ? Wq : (p == 1) ? Wk : Wv;
  const float* A = (p == 0) ? Aq : (p == 1) ? Ak : Av;
  const float* B = (p == 0) ? Bq : (p == 1) ? Bk : Bv;
  int idx = blockIdx.x * 256 + threadIdx.x;      // 0 .. 1M-1
  int o = idx >> 10, h = idx & 1023;
  float acc = W[idx];
#pragma unroll
  for (int r = 0; r < 8; ++r)
    acc += 2.0f * B[o * 8 + r] * A[r * H_ + h];  // SCALING = 16/8 = 2
  Weff[p * (H_ * H_) + idx] = f2bf(acc);
}

// ---------------- x fp32 -> bf16 ----------------
__global__ void convert_x(const float* __restrict__ x, unsigned short* __restrict__ Xb) {
  int i = (blockIdx.x * 256 + threadIdx.x) * 8;
  f32x4 a = *(const f32x4*)(x + i);
  f32x4 c = *(const f32x4*)(x + i + 4);
  uint4 rv;
  rv.x = (unsigned)f2bf(a[0]) | ((unsigned)f2bf(a[1]) << 16);
  rv.y = (unsigned)f2bf(a[2]) | ((unsigned)f2bf(a[3]) << 16);
  rv.z = (unsigned)f2bf(c[0]) | ((unsigned)f2bf(c[1]) << 16);
  rv.w = (unsigned)f2bf(c[2]) | ((unsigned)f2bf(c[3]) << 16);
  *(uint4*)(Xb + i) = rv;
}

// ---------------- QKV GEMM: C[m,n] = sum_k Xb[m,k] * Weff[n,k] (+bias) ----------------
// Epilogue: q scaled by 1/8 (softmax scale folded); V stored PRE-PERMUTED so attn's
// PV A-fragment is a single contiguous 16B load (slot map = P's natural map).
#define BM 128
#define BN 128
#define BK 32
__global__ __launch_bounds__(256) void gemm_qkv(
    const unsigned short* __restrict__ Xb, const unsigned short* __restrict__ Weff,
    const float* __restrict__ bq, const float* __restrict__ bk, const float* __restrict__ bv,
    unsigned short* __restrict__ qq, unsigned short* __restrict__ kk, unsigned short* __restrict__ vP) {
  __shared__ __align__(16) unsigned short As[BM][BK];
  __shared__ __align__(16) unsigned short Bs[BN][BK];
  int tid = threadIdx.x;
  int m0 = blockIdx.y * BM;
  int n0 = blockIdx.x * BN;
  int w = tid >> 6, l = tid & 63;
  int wm = w >> 1, wn = w & 1;
  int lr = l & 15, lg = l >> 4;

  f32x4 acc[4][4] = {};
  for (int kt = 0; kt < H_ / BK; ++kt) {
    __syncthreads();
#pragma unroll
    for (int i = 0; i < 2; ++i) {
      int c = tid + i * 256;                     // 512 16B chunks per tile
      int row = c >> 2, ks = (c & 3) * 8;
      const unsigned short* ga = Xb + (size_t)(m0 + row) * H_ + kt * BK + ks;
      const unsigned short* gb = Weff + (size_t)(n0 + row) * H_ + kt * BK + ks;
      __builtin_amdgcn_global_load_lds((const __attribute__((address_space(1))) void*)ga,
                                       (__attribute__((address_space(3))) void*)(&As[0][0] + c * 8), 16, 0, 0);
      __builtin_amdgcn_global_load_lds((const __attribute__((address_space(1))) void*)gb,
                                       (__attribute__((address_space(3))) void*)(&Bs[0][0] + c * 8), 16, 0, 0);
    }
    __syncthreads();
    bf16x8 af[4], bf[4];
#pragma unroll
    for (int f = 0; f < 4; ++f) {
      af[f] = *(const bf16x8*)&As[wm * 64 + f * 16 + lr][lg * 8];
      bf[f] = *(const bf16x8*)&Bs[wn * 64 + f * 16 + lr][lg * 8];
    }
#pragma unroll
    for (int fm = 0; fm < 4; ++fm)
#pragma unroll
      for (int fn = 0; fn < 4; ++fn)
        acc[fm][fn] = __builtin_amdgcn_mfma_f32_16x16x32_bf16(af[fm], bf[fn], acc[fm][fn], 0, 0, 0);
  }

  int p = n0 >> 10;
  const float* bias = (p == 0) ? bq : (p == 1) ? bk : bv;
#pragma unroll
  for (int fm = 0; fm < 4; ++fm) {
    int mbase = m0 + wm * 64 + fm * 16 + lg * 4;
#pragma unroll
    for (int fn = 0; fn < 4; ++fn) {
      int o = (n0 & 1023) + wn * 64 + fn * 16 + lr;
      int hh = o >> 6, d = o & 63;
      float bv_ = bias[o];
#pragma unroll
      for (int r = 0; r < 4; ++r) {
        int m = mbase + r;
        int bb = m >> 11, t = m & 2047;
        float v = acc[fm][fn][r] + bv_;
        size_t bh = (size_t)(bb * NH_ + hh);
        if (p == 0) {
          qq[(bh * T_ + t) * HD_ + d] = f2bf(v * 0.125f);   // fold 1/sqrt(64)
        } else if (p == 1) {
          kk[(bh * T_ + t) * HD_ + d] = f2bf(v);
        } else {
          // permuted position within 32-key tile: slot(g,j,hi) = g*8 + j + hi*4
          int r5 = t & 31;
          int within = ((r5 >> 2) & 3) * 8 + (r5 & 3) + ((r5 >> 4) << 2);
          vP[(bh * HD_ + d) * T_ + (t & ~31) + within] = f2bf(v);
        }
      }
    }
  }
}

// ---------------- causal flash attention ----------------
// 1 wave per (bh, qt) 32-row Q-tile; 4096 waves (1024 blocks, all co-resident at
// 4 waves/SIMD). Balance by construction: each block's 4 waves take
// qt in {grp, 31-grp, 32+grp, 63-grp} (constant 130 tiles/block), rotated by
// (bh + grp>>2) so each SIMD hosts one wave of each size-class.
// K ping-pong prefetch (1 tile ahead); V/mask single-buffered, issued at step
// start (S-MFMA + softmax cover their latency). Zero-shuffle P->PV.
__global__ __launch_bounds__(256, 4) void attn_fwd(
    const unsigned short* __restrict__ qq, const unsigned short* __restrict__ kk,
    const unsigned short* __restrict__ vP, const float* __restrict__ mask,
    float* __restrict__ out) {
  int w = threadIdx.x >> 6, l = threadIdx.x & 63;
  int bid = blockIdx.x;
  int grp = bid >> 6, bh = bid & 63;
  int sel = (w + bh + (grp >> 2)) & 3;
  int qt = (sel == 0) ? grp : (sel == 1) ? (31 - grp) : (sel == 2) ? (32 + grp) : (63 - grp);
  int b = bh >> 4, h = bh & 15;
  int t0 = qt * 32;
  int nt = qt + 1;
  int lr = l & 15, g = l >> 4;
  const float L2E = 1.4426950408889634f;
  const float NINF = -__builtin_inff();

  const unsigned short* Kp = kk + (size_t)bh * T_ * HD_;
  const unsigned short* Vp = vP + (size_t)bh * HD_ * T_;
  const float* mp = mask + b * T_;
  const unsigned short* Qp = qq + ((size_t)bh * T_ + t0) * HD_;

  bf16x8 qf[2][2];
#pragma unroll
  for (int u = 0; u < 2; ++u)
#pragma unroll
    for (int hs = 0; hs < 2; ++hs)
      qf[u][hs] = *(const bf16x8*)(Qp + (u * 16 + lr) * HD_ + hs * 32 + g * 8);

  f32x4 accO[2][4] = {};
  float m_run[2] = {NINF, NINF};
  float l_run[2] = {0.f, 0.f};

  // K ping-pong buffers (named, static-indexed)
  bf16x8 kA0[2], kA1[2], kB0[2], kB1[2];

  auto load_k = [&](int k0, bf16x8 (&kd0)[2], bf16x8 (&kd1)[2]) {
#pragma unroll
    for (int hs = 0; hs < 2; ++hs) {
      kd0[hs] = *(const bf16x8*)(Kp + (size_t)(k0 + lr) * HD_ + hs * 32 + g * 8);
      kd1[hs] = *(const bf16x8*)(Kp + (size_t)(k0 + 16 + lr) * HD_ + hs * 32 + g * 8);
    }
  };

  auto step = [&](int ti, bf16x8 (&kc0)[2], bf16x8 (&kc1)[2],
                  bf16x8 (&kn0)[2], bf16x8 (&kn1)[2]) {
    int k0 = ti * 32;
    // issue current-tile V + mask loads now; consumed after S-MFMA + softmax
    bf16x8 vC[4];
#pragma unroll
    for (int dn = 0; dn < 4; ++dn)
      vC[dn] = *(const bf16x8*)(Vp + (size_t)(dn * 16 + lr) * T_ + k0 + g * 8);
    f32x4 mc0 = *(const f32x4*)(mp + k0 + g * 4);
    f32x4 mc1 = *(const f32x4*)(mp + k0 + 16 + g * 4);

    f32x4 s0[2] = {{0.f,0.f,0.f,0.f},{0.f,0.f,0.f,0.f}};
    f32x4 s1[2] = {{0.f,0.f,0.f,0.f},{0.f,0.f,0.f,0.f}};
    __builtin_amdgcn_s_setprio(1);
#pragma unroll
    for (int u = 0; u < 2; ++u)
#pragma unroll
      for (int hs = 0; hs < 2; ++hs) {
        s0[u] = __builtin_amdgcn_mfma_f32_16x16x32_bf16(kc0[hs], qf[u][hs], s0[u], 0, 0, 0);
        s1[u] = __builtin_amdgcn_mfma_f32_16x16x32_bf16(kc1[hs], qf[u][hs], s1[u], 0, 0, 0);
      }
    __builtin_amdgcn_s_setprio(0);
    // prefetch next k-tile's K into the other buffer
    if (ti + 1 < nt) load_k(k0 + 32, kn0, kn1);

    bool diag = (ti == nt - 1);
#pragma unroll
    for (int u = 0; u < 2; ++u) {
      float sc0[4], sc1[4];
      if (diag) {
        int qrow = t0 + u * 16 + lr;
#pragma unroll
        for (int r = 0; r < 4; ++r) {
          int ka = k0 + g * 4 + r;
          sc0[r] = (ka <= qrow)      ? s0[u][r] + mc0[r] : NINF;
          sc1[r] = (ka + 16 <= qrow) ? s1[u][r] + mc1[r] : NINF;
        }
      } else {
#pragma unroll
        for (int r = 0; r < 4; ++r) {
          sc0[r] = s0[u][r] + mc0[r];
          sc1[r] = s1[u][r] + mc1[r];
        }
      }
      float pm = fmaxf(fmaxf(fmaxf(sc0[0], sc0[1]), fmaxf(sc0[2], sc0[3])),
                       fmaxf(fmaxf(sc1[0], sc1[1]), fmaxf(sc1[2], sc1[3])));
      pm = fmaxf(pm, __shfl_xor(pm, 16));
      pm = fmaxf(pm, __shfl_xor(pm, 32));
      // defer-max (T13, THR=8)
      if (!__all(pm <= m_run[u] + 8.f)) {
        float m_new = fmaxf(m_run[u], pm);
        float alpha = exp2f((m_run[u] - m_new) * L2E);
        l_run[u] *= alpha;
#pragma unroll
        for (int dn = 0; dn < 4; ++dn)
#pragma unroll
          for (int r = 0; r < 4; ++r) accO[u][dn][r] *= alpha;
        m_run[u] = m_new;
      }
      float p0[4], p1[4], rsl = 0.f;
#pragma unroll
      for (int r = 0; r < 4; ++r) {
        p0[r] = exp2f((sc0[r] - m_run[u]) * L2E);
        p1[r] = exp2f((sc1[r] - m_run[u]) * L2E);
        rsl += p0[r] + p1[r];
      }
      l_run[u] += rsl;                            // lane-local; reduced once at end
      bf16x8 pv_;
#pragma unroll
      for (int r = 0; r < 4; ++r) {
        pv_[r]     = (__bf16)p0[r];
        pv_[4 + r] = (__bf16)p1[r];
      }
      __builtin_amdgcn_s_setprio(1);
#pragma unroll
      for (int dn = 0; dn < 4; ++dn)
        accO[u][dn] = __builtin_amdgcn_mfma_f32_16x16x32_bf16(vC[dn], pv_, accO[u][dn], 0, 0, 0);
      __builtin_amdgcn_s_setprio(0);
    }
  };

  load_k(0, kA0, kA1);
  int ti = 0;
  for (;;) {
    step(ti, kA0, kA1, kB0, kB1);
    if (++ti == nt) break;
    step(ti, kB0, kB1, kA0, kA1);
    if (++ti == nt) break;
  }

#pragma unroll
  for (int u = 0; u < 2; ++u) {
    float lt = l_run[u];
    lt += __shfl_xor(lt, 16);
    lt += __shfl_xor(lt, 32);
    float inv = 1.0f / lt;
    float* op = out + ((size_t)b * T_ + t0 + u * 16 + lr) * H_ + h * HD_;
#pragma unroll
    for (int dn = 0; dn < 4; ++dn) {
      f32x4 ov;
#pragma unroll
      for (int r = 0; r < 4; ++r) ov[r] = accO[u][dn][r] * inv;
      *(f32x4*)(op + dn * 16 + g * 4) = ov;
    }
  }
}

extern "C" void kernel_launch(void* const* d_in, const int* in_sizes, int n_in,
                              void* d_out, int out_size, void* d_ws, size_t ws_size,
                              hipStream_t stream) {
  const float* x    = (const float*)d_in[0];
  const float* mask = (const float*)d_in[1];
  const float* Wq = (const float*)d_in[2];
  const float* bq = (const float*)d_in[3];
  const float* Aq = (const float*)d_in[4];
  const float* Bq = (const float*)d_in[5];
  const float* Wk = (const float*)d_in[6];
  const float* bk = (const float*)d_in[7];
  const float* Ak = (const float*)d_in[8];
  const float* Bk = (const float*)d_in[9];
  const float* Wv = (const float*)d_in[10];
  const float* bv = (const float*)d_in[11];
  const float* Av = (const float*)d_in[12];
  const float* Bv = (const float*)d_in[13];
  float* out = (float*)d_out;

  char* ws = (char*)d_ws;
  unsigned short* Xb   = (unsigned short*)(ws);                   // 16 MB  [8192][1024]
  unsigned short* Weff = (unsigned short*)(ws + (16u << 20));     //  6 MB  [3][1024][1024]
  unsigned short* qq   = (unsigned short*)(ws + (22u << 20));     // 16 MB  [4][16][2048][64]
  unsigned short* kk   = (unsigned short*)(ws + (38u << 20));     // 16 MB  [4][16][2048][64]
  unsigned short* vP   = (unsigned short*)(ws + (54u << 20));     // 16 MB  [4][16][64][2048] (permuted tiles)

  prep_weights<<<dim3(4096, 3), 256, 0, stream>>>(Wq, Aq, Bq, Wk, Ak, Bk, Wv, Av, Bv, Weff);
  convert_x<<<4096, 256, 0, stream>>>(x, Xb);
  gemm_qkv<<<dim3(24, 64), 256, 0, stream>>>(Xb, Weff, bq, bk, bv, qq, kk, vP);
  attn_fwd<<<1024, 256, 0, stream>>>(qq, kk, vP, mask, out);
}

// Round 6
// 210.389 us; speedup vs baseline: 3.4423x; 1.8651x over previous
//
#include <hip/hip_runtime.h>
#include <stdint.h>

#define T_  2048
#define H_  1024
#define NH_ 16
#define HD_ 64

typedef __bf16 bf16x8 __attribute__((ext_vector_type(8)));
typedef float  f32x4  __attribute__((ext_vector_type(4)));

__device__ __forceinline__ unsigned short f2bf(float f) {
  unsigned u = __builtin_bit_cast(unsigned, f);
  u += 0x7fffu + ((u >> 16) & 1u);          // RNE
  return (unsigned short)(u >> 16);
}

// ---------------- W_eff = W + 2.0 * B@A  (LoRA fold), store bf16 ----------------
__global__ void prep_weights(const float* __restrict__ Wq, const float* __restrict__ Aq, const float* __restrict__ Bq,
                             const float* __restrict__ Wk, const float* __restrict__ Ak, const float* __restrict__ Bk,
                             const float* __restrict__ Wv, const float* __restrict__ Av, const float* __restrict__ Bv,
                             unsigned short* __restrict__ Weff) {
  int p = blockIdx.y;
  const float* W = (p == 0) ? Wq : (p == 1) ? Wk : Wv;
  const float* A = (p == 0) ? Aq : (p == 1) ? Ak : Av;
  const float* B = (p == 0) ? Bq : (p == 1) ? Bk : Bv;
  int idx = blockIdx.x * 256 + threadIdx.x;      // 0 .. 1M-1
  int o = idx >> 10, h = idx & 1023;
  float acc = W[idx];
#pragma unroll
  for (int r = 0; r < 8; ++r)
    acc += 2.0f * B[o * 8 + r] * A[r * H_ + h];  // SCALING = 16/8 = 2
  Weff[p * (H_ * H_) + idx] = f2bf(acc);
}

// ---------------- x fp32 -> bf16 ----------------
__global__ void convert_x(const float* __restrict__ x, unsigned short* __restrict__ Xb) {
  int i = (blockIdx.x * 256 + threadIdx.x) * 8;
  f32x4 a = *(const f32x4*)(x + i);
  f32x4 c = *(const f32x4*)(x + i + 4);
  uint4 rv;
  rv.x = (unsigned)f2bf(a[0]) | ((unsigned)f2bf(a[1]) << 16);
  rv.y = (unsigned)f2bf(a[2]) | ((unsigned)f2bf(a[3]) << 16);
  rv.z = (unsigned)f2bf(c[0]) | ((unsigned)f2bf(c[1]) << 16);
  rv.w = (unsigned)f2bf(c[2]) | ((unsigned)f2bf(c[3]) << 16);
  *(uint4*)(Xb + i) = rv;
}

// ---------------- QKV GEMM: C[m,n] = sum_k Xb[m,k] * Weff[n,k] (+bias) ----------------
// Epilogue: q scaled by 1/8 (softmax scale folded); V stored PRE-PERMUTED so attn's
// PV A-fragment is a single contiguous 16B load (slot map = P's natural map).
#define BM 128
#define BN 128
#define BK 32
__global__ __launch_bounds__(256) void gemm_qkv(
    const unsigned short* __restrict__ Xb, const unsigned short* __restrict__ Weff,
    const float* __restrict__ bq, const float* __restrict__ bk, const float* __restrict__ bv,
    unsigned short* __restrict__ qq, unsigned short* __restrict__ kk, unsigned short* __restrict__ vP) {
  __shared__ __align__(16) unsigned short As[BM][BK];
  __shared__ __align__(16) unsigned short Bs[BN][BK];
  int tid = threadIdx.x;
  int m0 = blockIdx.y * BM;
  int n0 = blockIdx.x * BN;
  int w = tid >> 6, l = tid & 63;
  int wm = w >> 1, wn = w & 1;
  int lr = l & 15, lg = l >> 4;

  f32x4 acc[4][4] = {};
  for (int kt = 0; kt < H_ / BK; ++kt) {
    __syncthreads();
#pragma unroll
    for (int i = 0; i < 2; ++i) {
      int c = tid + i * 256;                     // 512 16B chunks per tile
      int row = c >> 2, ks = (c & 3) * 8;
      const unsigned short* ga = Xb + (size_t)(m0 + row) * H_ + kt * BK + ks;
      const unsigned short* gb = Weff + (size_t)(n0 + row) * H_ + kt * BK + ks;
      __builtin_amdgcn_global_load_lds((const __attribute__((address_space(1))) void*)ga,
                                       (__attribute__((address_space(3))) void*)(&As[0][0] + c * 8), 16, 0, 0);
      __builtin_amdgcn_global_load_lds((const __attribute__((address_space(1))) void*)gb,
                                       (__attribute__((address_space(3))) void*)(&Bs[0][0] + c * 8), 16, 0, 0);
    }
    __syncthreads();
    bf16x8 af[4], bf[4];
#pragma unroll
    for (int f = 0; f < 4; ++f) {
      af[f] = *(const bf16x8*)&As[wm * 64 + f * 16 + lr][lg * 8];
      bf[f] = *(const bf16x8*)&Bs[wn * 64 + f * 16 + lr][lg * 8];
    }
#pragma unroll
    for (int fm = 0; fm < 4; ++fm)
#pragma unroll
      for (int fn = 0; fn < 4; ++fn)
        acc[fm][fn] = __builtin_amdgcn_mfma_f32_16x16x32_bf16(af[fm], bf[fn], acc[fm][fn], 0, 0, 0);
  }

  int p = n0 >> 10;
  const float* bias = (p == 0) ? bq : (p == 1) ? bk : bv;
#pragma unroll
  for (int fm = 0; fm < 4; ++fm) {
    int mbase = m0 + wm * 64 + fm * 16 + lg * 4;
#pragma unroll
    for (int fn = 0; fn < 4; ++fn) {
      int o = (n0 & 1023) + wn * 64 + fn * 16 + lr;
      int hh = o >> 6, d = o & 63;
      float bv_ = bias[o];
#pragma unroll
      for (int r = 0; r < 4; ++r) {
        int m = mbase + r;
        int bb = m >> 11, t = m & 2047;
        float v = acc[fm][fn][r] + bv_;
        size_t bh = (size_t)(bb * NH_ + hh);
        if (p == 0) {
          qq[(bh * T_ + t) * HD_ + d] = f2bf(v * 0.125f);   // fold 1/sqrt(64)
        } else if (p == 1) {
          kk[(bh * T_ + t) * HD_ + d] = f2bf(v);
        } else {
          // permuted position within 32-key tile: slot(g,j,hi) = g*8 + j + hi*4
          int r5 = t & 31;
          int within = ((r5 >> 2) & 3) * 8 + (r5 & 3) + ((r5 >> 4) << 2);
          vP[(bh * HD_ + d) * T_ + (t & ~31) + within] = f2bf(v);
        }
      }
    }
  }
}

// ---------------- causal flash attention, LDS-shared K/V ----------------
// Block = (bh, qt group {4g4..4g4+3}); wave w owns qt=4g4+w (32 rows); all waves
// lockstep over k-tiles 0..4g4+3, wave w computes while ti <= qt.
// Per tile: K(32x64) + V(64x32, vP order) staged once via global_load_lds into
// double-buffered LDS (16 KB), XOR-swizzled (m201 pattern: inverse-swizzled
// global source, swizzled read). Grid = 1024 blocks = capacity at 4 blk/CU.
__global__ __launch_bounds__(256, 4) void attn_fwd(
    const unsigned short* __restrict__ qq, const unsigned short* __restrict__ kk,
    const unsigned short* __restrict__ vP, const float* __restrict__ mask,
    float* __restrict__ out) {
  __shared__ __align__(16) char lds[2][8192];    // [buf][ K: 0..4095 | V: 4096..8191 ]

  int tid = threadIdx.x;
  int w = tid >> 6, l = tid & 63;
  int bid = blockIdx.x;
  int bh = bid & 63;
  int g4 = ((bid >> 6) + bh) & 15;               // interleave size classes
  int qt = g4 * 4 + w;
  int nt = qt + 1;                               // my k-tiles
  int ntmax = g4 * 4 + 4;                        // block lockstep k-tiles
  int b = bh >> 4, h = bh & 15;
  int t0 = qt * 32;
  int lr = l & 15, g = l >> 4;
  const float L2E = 1.4426950408889634f;
  const float NINF = -__builtin_inff();

  const unsigned short* Kp = kk + (size_t)bh * T_ * HD_;
  const unsigned short* Vp = vP + (size_t)bh * HD_ * T_;
  const float* mp = mask + b * T_;
  const unsigned short* Qp = qq + ((size_t)bh * T_ + t0) * HD_;

  bf16x8 qf[2][2];
#pragma unroll
  for (int u = 0; u < 2; ++u)
#pragma unroll
    for (int hs = 0; hs < 2; ++hs)
      qf[u][hs] = *(const bf16x8*)(Qp + (u * 16 + lr) * HD_ + hs * 32 + g * 8);

  f32x4 accO[2][4] = {};
  float m_run[2] = {NINF, NINF};
  float l_run[2] = {0.f, 0.f};

  // staging: K chunk = tid (row=tid>>3, slot=tid&7, swz ^row&7);
  //          V chunk = tid (paired-d rows: row'=tid>>3 holds d=2row',2row'+1;
  //                    slot8=tid&7, swz ^row'&7; content (sub,slot)=gs8>>2,gs8&3)
  int krow = tid >> 3, kslot = tid & 7;
  int kgs = kslot ^ (krow & 7);
  int vgs = kgs;                                  // same swizzle structure
  int vsub = vgs >> 2, vslot = vgs & 3;
  int vrow = (krow << 1) | vsub;                  // d-row 0..63

  auto stage = [&](int kt, int dst) {
    int k0 = kt * 32;
    const unsigned short* srcK = Kp + (size_t)(k0 + krow) * HD_ + kgs * 8;
    __builtin_amdgcn_global_load_lds((const __attribute__((address_space(1))) void*)srcK,
        (__attribute__((address_space(3))) void*)(&lds[dst][tid * 16]), 16, 0, 0);
    const unsigned short* srcV = Vp + (size_t)vrow * T_ + k0 + vslot * 8;
    __builtin_amdgcn_global_load_lds((const __attribute__((address_space(1))) void*)srcV,
        (__attribute__((address_space(3))) void*)(&lds[dst][4096 + tid * 16]), 16, 0, 0);
  };

  // per-lane read offsets (loop-invariant)
  int kswz = lr & 7;
  int vrd = (lr >> 1) & 7;                       // row'&7 for V reads
  int s8base = ((l & 1) << 2) | g;               // wrong lane decomp? no: sub=lr&1

  stage(0, 0);
  __syncthreads();

  for (int ti = 0; ti < ntmax; ++ti) {
    int cur = ti & 1;
    if (ti + 1 < ntmax) stage(ti + 1, cur ^ 1);

    if (ti < nt) {
      const char* kb = lds[cur];
      int k0 = ti * 32;
      f32x4 mc0 = *(const f32x4*)(mp + k0 + g * 4);
      f32x4 mc1 = *(const f32x4*)(mp + k0 + 16 + g * 4);

      f32x4 s0[2] = {{0.f,0.f,0.f,0.f},{0.f,0.f,0.f,0.f}};
      f32x4 s1[2] = {{0.f,0.f,0.f,0.f},{0.f,0.f,0.f,0.f}};
#pragma unroll
      for (int hs = 0; hs < 2; ++hs) {
        int sl = ((hs << 2) | g) ^ kswz;
        bf16x8 kc0 = *(const bf16x8*)(kb + lr * 128 + (sl << 4));
        bf16x8 kc1 = *(const bf16x8*)(kb + (16 + lr) * 128 + (sl << 4));
        __builtin_amdgcn_s_setprio(1);
#pragma unroll
        for (int u = 0; u < 2; ++u) {
          s0[u] = __builtin_amdgcn_mfma_f32_16x16x32_bf16(kc0, qf[u][hs], s0[u], 0, 0, 0);
          s1[u] = __builtin_amdgcn_mfma_f32_16x16x32_bf16(kc1, qf[u][hs], s1[u], 0, 0, 0);
        }
        __builtin_amdgcn_s_setprio(0);
      }

      bool diag = (ti == nt - 1);
      bf16x8 pv[2];
#pragma unroll
      for (int u = 0; u < 2; ++u) {
        float sc0[4], sc1[4];
        if (diag) {
          int qrow = t0 + u * 16 + lr;
#pragma unroll
          for (int r = 0; r < 4; ++r) {
            int ka = k0 + g * 4 + r;
            sc0[r] = (ka <= qrow)      ? s0[u][r] + mc0[r] : NINF;
            sc1[r] = (ka + 16 <= qrow) ? s1[u][r] + mc1[r] : NINF;
          }
        } else {
#pragma unroll
          for (int r = 0; r < 4; ++r) {
            sc0[r] = s0[u][r] + mc0[r];
            sc1[r] = s1[u][r] + mc1[r];
          }
        }
        float pm = fmaxf(fmaxf(fmaxf(sc0[0], sc0[1]), fmaxf(sc0[2], sc0[3])),
                         fmaxf(fmaxf(sc1[0], sc1[1]), fmaxf(sc1[2], sc1[3])));
        pm = fmaxf(pm, __shfl_xor(pm, 16));
        pm = fmaxf(pm, __shfl_xor(pm, 32));
        if (!__all(pm <= m_run[u] + 8.f)) {       // defer-max (T13, THR=8)
          float m_new = fmaxf(m_run[u], pm);
          float alpha = exp2f((m_run[u] - m_new) * L2E);
          l_run[u] *= alpha;
#pragma unroll
          for (int dn = 0; dn < 4; ++dn)
#pragma unroll
            for (int r = 0; r < 4; ++r) accO[u][dn][r] *= alpha;
          m_run[u] = m_new;
        }
        float rsl = 0.f;
#pragma unroll
        for (int r = 0; r < 4; ++r) {
          float p0 = exp2f((sc0[r] - m_run[u]) * L2E);
          float p1 = exp2f((sc1[r] - m_run[u]) * L2E);
          rsl += p0 + p1;
          pv[u][r]     = (__bf16)p0;
          pv[u][4 + r] = (__bf16)p1;
        }
        l_run[u] += rsl;                          // lane-local; reduced at end
      }

      // PV: V one fragment at a time from LDS (paired-d rows, 8-slot swizzle)
#pragma unroll
      for (int dn = 0; dn < 4; ++dn) {
        int rowp = dn * 8 + (lr >> 1);
        int sl = (((lr & 1) << 2) | g) ^ vrd;
        bf16x8 vf = *(const bf16x8*)(kb + 4096 + rowp * 128 + (sl << 4));
        __builtin_amdgcn_s_setprio(1);
#pragma unroll
        for (int u = 0; u < 2; ++u)
          accO[u][dn] = __builtin_amdgcn_mfma_f32_16x16x32_bf16(vf, pv[u], accO[u][dn], 0, 0, 0);
        __builtin_amdgcn_s_setprio(0);
      }
    }
    __syncthreads();
  }

#pragma unroll
  for (int u = 0; u < 2; ++u) {
    float lt = l_run[u];
    lt += __shfl_xor(lt, 16);
    lt += __shfl_xor(lt, 32);
    float inv = 1.0f / lt;
    float* op = out + ((size_t)b * T_ + t0 + u * 16 + lr) * H_ + h * HD_;
#pragma unroll
    for (int dn = 0; dn < 4; ++dn) {
      f32x4 ov;
#pragma unroll
      for (int r = 0; r < 4; ++r) ov[r] = accO[u][dn][r] * inv;
      *(f32x4*)(op + dn * 16 + g * 4) = ov;
    }
  }
  (void)s8base;
}

extern "C" void kernel_launch(void* const* d_in, const int* in_sizes, int n_in,
                              void* d_out, int out_size, void* d_ws, size_t ws_size,
                              hipStream_t stream) {
  const float* x    = (const float*)d_in[0];
  const float* mask = (const float*)d_in[1];
  const float* Wq = (const float*)d_in[2];
  const float* bq = (const float*)d_in[3];
  const float* Aq = (const float*)d_in[4];
  const float* Bq = (const float*)d_in[5];
  const float* Wk = (const float*)d_in[6];
  const float* bk = (const float*)d_in[7];
  const float* Ak = (const float*)d_in[8];
  const float* Bk = (const float*)d_in[9];
  const float* Wv = (const float*)d_in[10];
  const float* bv = (const float*)d_in[11];
  const float* Av = (const float*)d_in[12];
  const float* Bv = (const float*)d_in[13];
  float* out = (float*)d_out;

  char* ws = (char*)d_ws;
  unsigned short* Xb   = (unsigned short*)(ws);                   // 16 MB  [8192][1024]
  unsigned short* Weff = (unsigned short*)(ws + (16u << 20));     //  6 MB  [3][1024][1024]
  unsigned short* qq   = (unsigned short*)(ws + (22u << 20));     // 16 MB  [4][16][2048][64]
  unsigned short* kk   = (unsigned short*)(ws + (38u << 20));     // 16 MB  [4][16][2048][64]
  unsigned short* vP   = (unsigned short*)(ws + (54u << 20));     // 16 MB  [4][16][64][2048] (permuted tiles)

  prep_weights<<<dim3(4096, 3), 256, 0, stream>>>(Wq, Aq, Bq, Wk, Ak, Bk, Wv, Av, Bv, Weff);
  convert_x<<<4096, 256, 0, stream>>>(x, Xb);
  gemm_qkv<<<dim3(24, 64), 256, 0, stream>>>(Xb, Weff, bq, bk, bv, qq, kk, vP);
  attn_fwd<<<1024, 256, 0, stream>>>(qq, kk, vP, mask, out);
}